// Round 10
// baseline (397.142 us; speedup 1.0000x reference)
//
#include <hip/hip_runtime.h>

#define T_STEPS 512
#define HID 128
#define SEQS 2     // independent sequences interleaved per block
#define ROWS 16    // rows per sequence tile

typedef short bf16x8 __attribute__((ext_vector_type(8)));   // MFMA A/B frag (8 bf16)
typedef float f32x4  __attribute__((ext_vector_type(4)));   // MFMA C/D frag
typedef unsigned int u32;
typedef u32 u32x4 __attribute__((ext_vector_type(4)));

// LDS layout (bytes):
//   0     : seqA h buf0 [16 r][128 j] bf16 (4 KB, XOR-swizzled byte ^= (r&7)<<4)
//   4096  : seqA h buf1
//   8192  : seqB h buf0
//   12288 : seqB h buf1
//   16384 : red [2 seq][4 w][16 r] f32 (512 B)
#define LDS_BYTES (16384 + 512)

__device__ __forceinline__ u32 cvt_pk_bf16(float s0, float s1) {
    u32 d;  // d.lo = bf16(s0), d.hi = bf16(s1)
    asm("v_cvt_pk_bf16_f32 %0, %1, %2" : "=v"(d) : "v"(s0), "v"(s1));
    return d;
}
__device__ __forceinline__ bf16x8 frag_from(u32 a, u32 b, u32 c, u32 d) {
    u32x4 t = {a, b, c, d};
    return __builtin_bit_cast(bf16x8, t);
}
// tanh(a) = 1 - 2/(exp2(a*2*log2e)+1); 5 VALU ops, saturates correctly
__device__ __forceinline__ float tanh_fast(float a) {
    const float e = __builtin_amdgcn_exp2f(a * 2.885390081777926816f);
    const float r = __builtin_amdgcn_rcpf(e + 1.0f);
    return fmaf(-2.0f, r, 1.0f);
}

// split 8 f32 into hi/lo bf16 frags (W kept to ~2^-18 rel as Whi+Wlo)
#define SPLIT8(HI, LO, f0,f1,f2,f3,f4,f5,f6,f7) do {                          \
    u32 h0_ = cvt_pk_bf16(f0,f1), h1_ = cvt_pk_bf16(f2,f3);                   \
    u32 h2_ = cvt_pk_bf16(f4,f5), h3_ = cvt_pk_bf16(f6,f7);                   \
    float l0_ = (f0) - __uint_as_float(h0_ << 16);                            \
    float l1_ = (f1) - __uint_as_float(h0_ & 0xffff0000u);                    \
    float l2_ = (f2) - __uint_as_float(h1_ << 16);                            \
    float l3_ = (f3) - __uint_as_float(h1_ & 0xffff0000u);                    \
    float l4_ = (f4) - __uint_as_float(h2_ << 16);                            \
    float l5_ = (f5) - __uint_as_float(h2_ & 0xffff0000u);                    \
    float l6_ = (f6) - __uint_as_float(h3_ << 16);                            \
    float l7_ = (f7) - __uint_as_float(h3_ & 0xffff0000u);                    \
    u32 g0_ = cvt_pk_bf16(l0_,l1_), g1_ = cvt_pk_bf16(l2_,l3_);               \
    u32 g2_ = cvt_pk_bf16(l4_,l5_), g3_ = cvt_pk_bf16(l6_,l7_);               \
    HI = frag_from(h0_,h1_,h2_,h3_); LO = frag_from(g0_,g1_,g2_,g3_);         \
} while (0)

#define MFMA(ACC, A, B) \
    ACC = __builtin_amdgcn_mfma_f32_16x16x32_bf16(A, B, ACC, 0, 0, 0);

__global__ __launch_bounds__(256, 1)
__attribute__((amdgpu_waves_per_eu(1, 1)))
void rnn_mfma_kernel(const float* __restrict__ x,
                     const float* __restrict__ W_ih,
                     const float* __restrict__ W_hh,
                     const float* __restrict__ b_ih,
                     const float* __restrict__ b_hh,
                     const float* __restrict__ W_out,
                     const float* __restrict__ b_out,
                     float* __restrict__ y)
{
    __shared__ __align__(16) char lds[LDS_BYTES];

    const int tid = threadIdx.x;
    const int w   = tid >> 6;          // wave 0..3: owns j in [32w, 32w+32)
    const int l   = tid & 63;
    const int r   = l & 15;            // batch row within seq tile (B/C col)
    const int q   = l >> 4;            // lane quarter (k-group / C row group)
    const int b0A = blockIdx.x * (SEQS * ROWS);
    const int b0B = b0A + ROWS;

    // ---- zero h buf0 for both seqs
    {
        const u32x4 z = {0,0,0,0};
        *(u32x4*)&lds[tid * 16]        = z;   // seqA buf0
        *(u32x4*)&lds[8192 + tid * 16] = z;   // seqB buf0
    }

    // ---- W_hh A-fragments (16 named frags: 2 M-tiles x 4 K-chunks x hi/lo)
    bf16x8 Whi00,Whi01,Whi02,Whi03, Whi10,Whi11,Whi12,Whi13;
    bf16x8 Wlo00,Wlo01,Wlo02,Wlo03, Wlo10,Wlo11,Wlo12,Wlo13;
#define LOADW(HI, LO, TT, C) do {                                             \
    const float* p_ = W_hh + (size_t)(32*w + 16*(TT) + r) * HID + q*8 + (C)*32;\
    float4 fa_ = *(const float4*)p_;                                          \
    float4 fb_ = *(const float4*)(p_ + 4);                                    \
    SPLIT8(HI, LO, fa_.x,fa_.y,fa_.z,fa_.w, fb_.x,fb_.y,fb_.z,fb_.w);         \
} while (0)
    LOADW(Whi00,Wlo00,0,0); LOADW(Whi01,Wlo01,0,1);
    LOADW(Whi02,Wlo02,0,2); LOADW(Whi03,Wlo03,0,3);
    LOADW(Whi10,Wlo10,1,0); LOADW(Whi11,Wlo11,1,1);
    LOADW(Whi12,Wlo12,1,2); LOADW(Whi13,Wlo13,1,3);

    // ---- per-lane constants: this lane's 8 output j's
    const int j0 = 32 * w + 4 * q;          // tile0 rows 4q..4q+3 ; tile1 = +16
    const float4 wih0  = *(const float4*)(W_ih + j0);
    const float4 wih1  = *(const float4*)(W_ih + j0 + 16);
    float4 bias0, bias1;
    {
        const float4 bi0 = *(const float4*)(b_ih + j0);
        const float4 bh0 = *(const float4*)(b_hh + j0);
        const float4 bi1 = *(const float4*)(b_ih + j0 + 16);
        const float4 bh1 = *(const float4*)(b_hh + j0 + 16);
        bias0.x = bi0.x + bh0.x; bias0.y = bi0.y + bh0.y;
        bias0.z = bi0.z + bh0.z; bias0.w = bi0.w + bh0.w;
        bias1.x = bi1.x + bh1.x; bias1.y = bi1.y + bh1.y;
        bias1.z = bi1.z + bh1.z; bias1.w = bi1.w + bh1.w;
    }

    // ---- precomputed swizzled LDS offsets (relative to seq/parity base)
    const int swz   = (r & 7) << 4;
    const int voff0 = (r*256 + q*16 +   0) ^ swz;   // B-frag read, k-chunk c
    const int voff1 = (r*256 + q*16 +  64) ^ swz;
    const int voff2 = (r*256 + q*16 + 128) ^ swz;
    const int voff3 = (r*256 + q*16 + 192) ^ swz;
    const int woff0 = (r*256 + w*64 +      q*8) ^ swz;  // h write, tile0 (8B)
    const int woff1 = (r*256 + w*64 + 32 + q*8) ^ swz;  // tile1

    // ---- x pointers (per lane: row b0+r), 1-step-ahead clamped prefetch
    const float* xpA = x + (size_t)(b0A + r) * T_STEPS;
    const float* xpB = x + (size_t)(b0B + r) * T_STEPS;
    float xtA = xpA[0];
    float xtB = xpB[0];
    xpA += 1; xpB += 1;                 // point at t=1

    __syncthreads();

    u32 rbA = 0,    wbA = 4096;         // seqA read/write parity bases
    u32 rbB = 8192, wbB = 12288;        // seqB
    f32x4 hvA0, hvA1, hvB0, hvB1;       // last-step h (this lane's 8 j's per seq)

    for (int t = 0; t < T_STEPS; ++t) {
        // ---- B-frag reads, both seqs (8x ds_read_b128)
        bf16x8 BA0 = *(const bf16x8*)&lds[rbA + voff0];
        bf16x8 BA1 = *(const bf16x8*)&lds[rbA + voff1];
        bf16x8 BA2 = *(const bf16x8*)&lds[rbA + voff2];
        bf16x8 BA3 = *(const bf16x8*)&lds[rbA + voff3];
        bf16x8 BB0 = *(const bf16x8*)&lds[rbB + voff0];
        bf16x8 BB1 = *(const bf16x8*)&lds[rbB + voff1];
        bf16x8 BB2 = *(const bf16x8*)&lds[rbB + voff2];
        bf16x8 BB3 = *(const bf16x8*)&lds[rbB + voff3];

        // ---- prefetch x[t+1] (clamped; last iter re-reads t=511, unused)
        const float xnA = *xpA;
        const float xnB = *xpB;

        // ---- accumulators: per tile, chunkpair01 (init bias+x) / 23 (init 0)
        f32x4 aA0, aA1, aA2, aA3, aB0, aB1, aB2, aB3;
        aA0[0]=fmaf(xtA,wih0.x,bias0.x); aA0[1]=fmaf(xtA,wih0.y,bias0.y);
        aA0[2]=fmaf(xtA,wih0.z,bias0.z); aA0[3]=fmaf(xtA,wih0.w,bias0.w);
        aA2[0]=fmaf(xtA,wih1.x,bias1.x); aA2[1]=fmaf(xtA,wih1.y,bias1.y);
        aA2[2]=fmaf(xtA,wih1.z,bias1.z); aA2[3]=fmaf(xtA,wih1.w,bias1.w);
        aB0[0]=fmaf(xtB,wih0.x,bias0.x); aB0[1]=fmaf(xtB,wih0.y,bias0.y);
        aB0[2]=fmaf(xtB,wih0.z,bias0.z); aB0[3]=fmaf(xtB,wih0.w,bias0.w);
        aB2[0]=fmaf(xtB,wih1.x,bias1.x); aB2[1]=fmaf(xtB,wih1.y,bias1.y);
        aB2[2]=fmaf(xtB,wih1.z,bias1.z); aB2[3]=fmaf(xtB,wih1.w,bias1.w);
        aA1 = (f32x4)(0.0f); aA3 = (f32x4)(0.0f);
        aB1 = (f32x4)(0.0f); aB3 = (f32x4)(0.0f);

        // ---- 32 MFMAs: 8 chains (2 seq x 2 tiles x 2 chunkpairs), depth 4,
        // round-robin issue so dependent MFMAs are 8 issues apart
        MFMA(aA0, Whi00, BA0) MFMA(aA2, Whi10, BA0)
        MFMA(aB0, Whi00, BB0) MFMA(aB2, Whi10, BB0)
        MFMA(aA1, Whi02, BA2) MFMA(aA3, Whi12, BA2)
        MFMA(aB1, Whi02, BB2) MFMA(aB3, Whi12, BB2)

        MFMA(aA0, Wlo00, BA0) MFMA(aA2, Wlo10, BA0)
        MFMA(aB0, Wlo00, BB0) MFMA(aB2, Wlo10, BB0)
        MFMA(aA1, Wlo02, BA2) MFMA(aA3, Wlo12, BA2)
        MFMA(aB1, Wlo02, BB2) MFMA(aB3, Wlo12, BB2)

        MFMA(aA0, Whi01, BA1) MFMA(aA2, Whi11, BA1)
        MFMA(aB0, Whi01, BB1) MFMA(aB2, Whi11, BB1)
        MFMA(aA1, Whi03, BA3) MFMA(aA3, Whi13, BA3)
        MFMA(aB1, Whi03, BB3) MFMA(aB3, Whi13, BB3)

        MFMA(aA0, Wlo01, BA1) MFMA(aA2, Wlo11, BA1)
        MFMA(aB0, Wlo01, BB1) MFMA(aB2, Wlo11, BB1)
        MFMA(aA1, Wlo03, BA3) MFMA(aA3, Wlo13, BA3)
        MFMA(aB1, Wlo03, BB3) MFMA(aB3, Wlo13, BB3)

        // ---- finish: combine chunkpairs, tanh, pack, write
        const f32x4 sA0 = aA0 + aA1;
        const f32x4 sA1 = aA2 + aA3;
        const f32x4 sB0 = aB0 + aB1;
        const f32x4 sB1 = aB2 + aB3;
        hvA0[0]=tanh_fast(sA0[0]); hvA0[1]=tanh_fast(sA0[1]);
        hvA0[2]=tanh_fast(sA0[2]); hvA0[3]=tanh_fast(sA0[3]);
        hvA1[0]=tanh_fast(sA1[0]); hvA1[1]=tanh_fast(sA1[1]);
        hvA1[2]=tanh_fast(sA1[2]); hvA1[3]=tanh_fast(sA1[3]);
        hvB0[0]=tanh_fast(sB0[0]); hvB0[1]=tanh_fast(sB0[1]);
        hvB0[2]=tanh_fast(sB0[2]); hvB0[3]=tanh_fast(sB0[3]);
        hvB1[0]=tanh_fast(sB1[0]); hvB1[1]=tanh_fast(sB1[1]);
        hvB1[2]=tanh_fast(sB1[2]); hvB1[3]=tanh_fast(sB1[3]);

        *(uint2*)&lds[wbA + woff0] =
            make_uint2(cvt_pk_bf16(hvA0[0],hvA0[1]), cvt_pk_bf16(hvA0[2],hvA0[3]));
        *(uint2*)&lds[wbA + woff1] =
            make_uint2(cvt_pk_bf16(hvA1[0],hvA1[1]), cvt_pk_bf16(hvA1[2],hvA1[3]));
        *(uint2*)&lds[wbB + woff0] =
            make_uint2(cvt_pk_bf16(hvB0[0],hvB0[1]), cvt_pk_bf16(hvB0[2],hvB0[3]));
        *(uint2*)&lds[wbB + woff1] =
            make_uint2(cvt_pk_bf16(hvB1[0],hvB1[1]), cvt_pk_bf16(hvB1[2],hvB1[3]));

        // ---- advance x (clamped so last prefetch re-reads t=511, not OOB)
        const int adv = (t < T_STEPS - 2) ? 1 : 0;
        xtA = xnA; xtB = xnB;
        xpA += adv; xpB += adv;

        rbA ^= 4096; wbA ^= 4096;
        rbB ^= 4096; wbB ^= 4096;
        __syncthreads();
    }

    // ---- y = h_last . W_out + b_out, per seq
    const float4 wo0 = *(const float4*)(W_out + j0);
    const float4 wo1 = *(const float4*)(W_out + j0 + 16);
    float vA = wo0.x*hvA0[0] + wo0.y*hvA0[1] + wo0.z*hvA0[2] + wo0.w*hvA0[3]
             + wo1.x*hvA1[0] + wo1.y*hvA1[1] + wo1.z*hvA1[2] + wo1.w*hvA1[3];
    float vB = wo0.x*hvB0[0] + wo0.y*hvB0[1] + wo0.z*hvB0[2] + wo0.w*hvB0[3]
             + wo1.x*hvB1[0] + wo1.y*hvB1[1] + wo1.z*hvB1[2] + wo1.w*hvB1[3];
    vA += __shfl_xor(vA, 16, 64); vA += __shfl_xor(vA, 32, 64);
    vB += __shfl_xor(vB, 16, 64); vB += __shfl_xor(vB, 32, 64);
    if (q == 0) {
        *(float*)&lds[16384 +       (w * 16 + r) * 4] = vA;
        *(float*)&lds[16384 + 256 + (w * 16 + r) * 4] = vB;
    }
    __syncthreads();
    if (tid < 32) {
        const int s  = tid >> 4, rr = tid & 15;
        const u32 base = 16384u + (u32)s * 256u + (u32)rr * 4u;
        const float sum = *(const float*)&lds[base]
                        + *(const float*)&lds[base + 64]
                        + *(const float*)&lds[base + 128]
                        + *(const float*)&lds[base + 192];
        y[b0A + s * ROWS + rr] = sum + b_out[0];
    }
}

extern "C" void kernel_launch(void* const* d_in, const int* in_sizes, int n_in,
                              void* d_out, int out_size, void* d_ws, size_t ws_size,
                              hipStream_t stream)
{
    const float* x     = (const float*)d_in[0];
    const float* W_ih  = (const float*)d_in[1];
    const float* W_hh  = (const float*)d_in[2];
    const float* b_ih  = (const float*)d_in[3];
    const float* b_hh  = (const float*)d_in[4];
    const float* W_out = (const float*)d_in[5];
    const float* b_out = (const float*)d_in[6];
    float* y = (float*)d_out;

    const int B = in_sizes[0] / T_STEPS;   // 1024
    rnn_mfma_kernel<<<B / (SEQS * ROWS), 256, 0, stream>>>(
        x, W_ih, W_hh, b_ih, b_hh, W_out, b_out, y);
}